// Round 2
// baseline (11427.620 us; speedup 1.0000x reference)
//
#include <hip/hip_runtime.h>
#include <hip/hip_bf16.h>

// Bidirectional LSTM, B=256, S=256, E=300, H=512.
// Persistent cooperative scan: 256 WGs = 2 dir x 4 batch-tiles(64) x 32 col-tiles(16 h-cols).
// W' tile (64 gate-rows x 832 K) resident in LDS (119.8 KB) for all 256 steps.
// A fragments loaded straight from global in MFMA layout (coalesced 64B segments); no K-loop syncs.
// c kept in registers (exclusively owned). Per-step sync = per-WG flag words (store-release + poll),
// one 256B-padded line-pair per 32-WG group. xe-chunk MFMAs overlap the barrier wait.

#define SQ 256
#define NB 256
#define HD 512
#define ED 300
#define EP 320
#define KW 832   // 512 + 320
#define G4 2048

typedef __attribute__((ext_vector_type(8))) short bf16x8;
typedef __attribute__((ext_vector_type(4))) float f32x4;

__device__ __forceinline__ unsigned short f2bf(float x) {
  union { float f; unsigned u; } v; v.f = x;
  unsigned r = v.u + 0x7FFFu + ((v.u >> 16) & 1u);
  return (unsigned short)(r >> 16);
}
__device__ __forceinline__ float sigf(float x) { return 1.f / (1.f + __expf(-x)); }
__device__ __forceinline__ float tanhf_(float x) {
  float t = __expf(-2.f * fabsf(x));
  float r = (1.f - t) / (1.f + t);
  return x < 0.f ? -r : r;
}

__global__ void k_zero(unsigned* __restrict__ p, int n) {
  int i = blockIdx.x * 256 + threadIdx.x;
  if (i < n) p[i] = 0u;
}

// W' bf16 [2][2048][832] = [W_hh | W_ih | 0-pad] per gate row
__global__ void k_prep_w(const float* __restrict__ Wihf, const float* __restrict__ Whhf,
                         const float* __restrict__ Wihb, const float* __restrict__ Whhb,
                         unsigned short* __restrict__ Wp) {
  int idx = blockIdx.x * 256 + threadIdx.x;
  if (idx >= 2 * G4 * KW) return;
  int d = idx / (G4 * KW);
  int rem = idx % (G4 * KW);
  int R = rem / KW, k = rem % KW;
  const float* Whh = d ? Whhb : Whhf;
  const float* Wih = d ? Wihb : Wihf;
  float v = 0.f;
  if (k < HD) v = Whh[R * HD + k];
  else if (k < HD + ED) v = Wih[R * ED + (k - HD)];
  Wp[idx] = f2bf(v);
}

// xe bf16 [S][B][320] = emb[tok] padded
__global__ void k_prep_xe(const int* __restrict__ x, const float* __restrict__ emb,
                          unsigned short* __restrict__ xe) {
  const int bidx = blockIdx.x;           // t*NB + b
  const int t = bidx / NB, b = bidx % NB;
  const int tok = x[b * SQ + t];         // x is (B,1,S)
  unsigned short* dst = xe + (size_t)(t * NB + b) * EP;
  const float* src = emb + (size_t)tok * ED;
  for (int e = threadIdx.x; e < EP; e += 64)
    dst[e] = (e < ED) ? f2bf(src[e]) : (unsigned short)0;
}

#define MFMA __builtin_amdgcn_mfma_f32_16x16x32_bf16

__global__ __launch_bounds__(256, 1) void lstm_scan(
    const unsigned short* __restrict__ Wp,    // [2][2048][832] bf16
    const unsigned short* __restrict__ xe,    // [S][B][320] bf16
    const float* __restrict__ bias_f,
    const float* __restrict__ bias_b,
    unsigned short* __restrict__ hbuf,        // [2 parity][2 dir][B][H] bf16
    float* __restrict__ hfin,                 // [2][B][H] f32
    unsigned* __restrict__ flags)             // [8 groups][64] ints (256B stride)
{
  extern __shared__ unsigned short wlds[];    // [13][64][72] bf16 = 119808 B
  const int p = blockIdx.x;
  const int g8 = p & 7;        // group id (d,bg); p%8 -> same XCD round-robin
  const int d  = g8 >> 2;
  const int bg = g8 & 3;
  const int ct = p >> 3;       // col tile (16 h-cols), 0..31
  const int tid = threadIdx.x;
  const int lane = tid & 63;
  const int wv = tid >> 6;     // wave -> batch sub-block of 16
  const int q = lane >> 4;     // k-slice 0..3
  const int lm = lane & 15;

  // ---- load W' tile resident into LDS (once) ----
  {
    const unsigned short* wsrc = Wp + (size_t)d * G4 * KW;
    for (int u = tid; u < 13 * 64 * 8; u += 256) {
      int ch  = u >> 9;          // chunk 0..12
      int rem = u & 511;
      int row = rem >> 3, c16 = rem & 7;
      int R = ((row >> 4) << 9) + (ct << 4) + (row & 15);  // gate*512 + ct*16 + j
      bf16x8 v = *(const bf16x8*)(wsrc + (size_t)R * KW + (ch << 6) + (c16 << 3));
      *(bf16x8*)&wlds[(ch * 64 + row) * 72 + (c16 << 3)] = v;
    }
  }
  __syncthreads();

  const float* bias = d ? bias_b : bias_f;
  const int ncol = (ct << 4) | lm;
  const float Bi = bias[ncol];
  const float Bf = bias[512 + ncol];
  const float Bg = bias[1024 + ncol];
  const float Bo = bias[1536 + ncol];

  float cr[4] = {0.f, 0.f, 0.f, 0.f};        // cell state, register-resident
  const int arow = wv * 16 + lm;             // A row within 64-row tile

  for (int t = 0; t < SQ; ++t) {
    const int tx = d ? (SQ - 1 - t) : t;
    f32x4 acc0 = {Bi, Bi, Bi, Bi};
    f32x4 acc1 = {Bf, Bf, Bf, Bf};
    f32x4 acc2 = {Bg, Bg, Bg, Bg};
    f32x4 acc3 = {Bo, Bo, Bo, Bo};

    // ---- xe phase (K cols 512..831): independent of h, overlaps barrier ----
    const unsigned short* xrow = xe + ((size_t)tx * NB + bg * 64 + arow) * EP + (q << 3);
    #pragma unroll
    for (int ch = 0; ch < 5; ++ch) {
      #pragma unroll
      for (int kk = 0; kk < 2; ++kk) {
        bf16x8 a = *(const bf16x8*)(xrow + (ch << 6) + (kk << 5));
        const unsigned short* wb = &wlds[((8 + ch) * 64) * 72 + (q << 3) + (kk << 5)];
        bf16x8 b0 = *(const bf16x8*)&wb[(     lm) * 72];
        bf16x8 b1 = *(const bf16x8*)&wb[(16 + lm) * 72];
        bf16x8 b2 = *(const bf16x8*)&wb[(32 + lm) * 72];
        bf16x8 b3 = *(const bf16x8*)&wb[(48 + lm) * 72];
        acc0 = MFMA(a, b0, acc0, 0, 0, 0);
        acc1 = MFMA(a, b1, acc1, 0, 0, 0);
        acc2 = MFMA(a, b2, acc2, 0, 0, 0);
        acc3 = MFMA(a, b3, acc3, 0, 0, 0);
      }
    }

    // ---- wait for step t-1 completion (all 32 WGs of this group) ----
    if (t > 0) {
      if (tid < 64) {
        const unsigned tgt = (unsigned)t;
        while (1) {
          unsigned v = 0xFFFFFFFFu;
          if (lane < 32)
            v = __hip_atomic_load(&flags[g8 * 64 + lane], __ATOMIC_RELAXED, __HIP_MEMORY_SCOPE_AGENT);
          if (__all((int)(v >= tgt))) break;
          __builtin_amdgcn_s_sleep(1);
        }
      }
      __syncthreads();
      __threadfence();   // acquire: make other CUs' h(t-1) visible (L1 inv)
    }

    // ---- h phase (K cols 0..511) ----
    const unsigned short* hrow =
        hbuf + ((size_t)((t & 1) * 2 + d) * NB + bg * 64 + arow) * HD + (q << 3);
    #pragma unroll
    for (int ch = 0; ch < 8; ++ch) {
      #pragma unroll
      for (int kk = 0; kk < 2; ++kk) {
        bf16x8 a = *(const bf16x8*)(hrow + (ch << 6) + (kk << 5));
        const unsigned short* wb = &wlds[(ch * 64) * 72 + (q << 3) + (kk << 5)];
        bf16x8 b0 = *(const bf16x8*)&wb[(     lm) * 72];
        bf16x8 b1 = *(const bf16x8*)&wb[(16 + lm) * 72];
        bf16x8 b2 = *(const bf16x8*)&wb[(32 + lm) * 72];
        bf16x8 b3 = *(const bf16x8*)&wb[(48 + lm) * 72];
        acc0 = MFMA(a, b0, acc0, 0, 0, 0);
        acc1 = MFMA(a, b1, acc1, 0, 0, 0);
        acc2 = MFMA(a, b2, acc2, 0, 0, 0);
        acc3 = MFMA(a, b3, acc3, 0, 0, 0);
      }
    }

    // ---- epilogue: gate nonlinearity, c in regs, write h(t) ----
    unsigned short* hout = hbuf + ((size_t)(((t & 1) ^ 1) * 2 + d) * NB) * HD;
    #pragma unroll
    for (int r = 0; r < 4; ++r) {
      const int brow = bg * 64 + wv * 16 + q * 4 + r;
      const float gi = acc0[r], gf = acc1[r], gg = acc2[r], go = acc3[r];
      float c = sigf(gf) * cr[r] + sigf(gi) * tanhf_(gg);
      float h = sigf(go) * tanhf_(c);
      cr[r] = c;
      hout[(size_t)brow * HD + ncol] = f2bf(h);
      if (t == SQ - 1) hfin[(d * NB + brow) * HD + ncol] = h;
    }

    // ---- arrive: release own flag ----
    __threadfence();
    __syncthreads();
    if (tid == 0)
      __hip_atomic_store(&flags[g8 * 64 + ct], (unsigned)(t + 1),
                         __ATOMIC_RELEASE, __HIP_MEMORY_SCOPE_AGENT);
  }
}

__global__ void k_out(const float* __restrict__ hfin, const float* __restrict__ Wo,
                      const float* __restrict__ bo, float* __restrict__ out) {
  const int b = blockIdx.x;
  const int tid = threadIdx.x;
  float s = 0.f;
  for (int k = tid; k < 1024; k += 256)
    s += hfin[((k >> 9) * NB + b) * HD + (k & 511)] * Wo[k];
  #pragma unroll
  for (int o = 32; o > 0; o >>= 1) s += __shfl_down(s, o, 64);
  __shared__ float red[4];
  if ((tid & 63) == 0) red[tid >> 6] = s;
  __syncthreads();
  if (tid == 0) out[b] = red[0] + red[1] + red[2] + red[3] + bo[0];
}

extern "C" void kernel_launch(void* const* d_in, const int* in_sizes, int n_in,
                              void* d_out, int out_size, void* d_ws, size_t ws_size,
                              hipStream_t stream) {
  const int*   x    = (const int*)d_in[0];
  const float* emb  = (const float*)d_in[1];
  const float* Wihf = (const float*)d_in[2];
  const float* Whhf = (const float*)d_in[3];
  const float* bf   = (const float*)d_in[4];
  const float* Wihb = (const float*)d_in[5];
  const float* Whhb = (const float*)d_in[6];
  const float* bb   = (const float*)d_in[7];
  const float* Wo   = (const float*)d_in[8];
  const float* bo   = (const float*)d_in[9];
  float* out = (float*)d_out;

  // ws layout:
  //   Wp    @ 0          : 2*2048*832*2  = 6,815,744
  //   xe    @ 6,815,744  : 256*256*320*2 = 41,943,040
  //   hbuf  @ 48,758,784 : 2*2*256*512*2 = 1,048,576
  //   flags @ 49,807,360 : 8*64*4        = 2,048
  //   hfin  @ 49,809,408 : 2*256*512*4   = 1,048,576
  char* ws = (char*)d_ws;
  unsigned short* Wp   = (unsigned short*)(ws + 0);
  unsigned short* xe   = (unsigned short*)(ws + 6815744);
  unsigned short* hbuf = (unsigned short*)(ws + 48758784);
  unsigned*       flg  = (unsigned*)(ws + 49807360);
  float*          hfin = (float*)(ws + 49809408);

  // zero hbuf + flags (contiguous 1,050,624 B = 262,656 words)
  k_zero<<<1026, 256, 0, stream>>>((unsigned*)(ws + 48758784), 262656);
  k_prep_w<<<(2 * G4 * KW + 255) / 256, 256, 0, stream>>>(Wihf, Whhf, Wihb, Whhb, Wp);
  k_prep_xe<<<SQ * NB, 64, 0, stream>>>(x, emb, xe);

  const int ldsBytes = 13 * 64 * 72 * 2;  // 119,808
  hipFuncSetAttribute((const void*)lstm_scan,
                      hipFuncAttributeMaxDynamicSharedMemorySize, ldsBytes);

  void* args[] = { (void*)&Wp, (void*)&xe, (void*)&bf, (void*)&bb,
                   (void*)&hbuf, (void*)&hfin, (void*)&flg };
  hipLaunchCooperativeKernel((const void*)lstm_scan, dim3(256), dim3(256), args,
                             ldsBytes, stream);

  k_out<<<NB, 256, 0, stream>>>(hfin, Wo, bo, out);
}

// Round 3
// 1713.910 us; speedup vs baseline: 6.6676x; 6.6676x over previous
//
#include <hip/hip_runtime.h>
#include <hip/hip_bf16.h>

// Bidirectional LSTM, B=256, S=256, E=300, H=512.
// Persistent cooperative scan: 256 WGs = 2 dir x 4 batch-tiles(64) x 32 col-tiles(16 h-cols).
// W' tile resident in LDS (XOR-swizzled, 106.5 KB) for all 256 steps.
// Cross-WG h exchange goes through the Infinity Cache via per-instruction sc0|sc1 cache bits
// (NO __threadfence -> no full-L2 writeback/invalidate). Per-step sync = per-WG flag words.
// c lives in registers. xe-phase MFMAs (K=512..831, h-independent) run before the poll.

#define SQ 256
#define NB 256
#define HD 512
#define ED 300
#define EP 320
#define KW 832   // 512 + 320
#define G4 2048

typedef __attribute__((ext_vector_type(8))) short bf16x8;
typedef __attribute__((ext_vector_type(4))) float f32x4;
typedef __attribute__((ext_vector_type(4))) int i32x4;

__device__ __forceinline__ unsigned short f2bf(float x) {
  union { float f; unsigned u; } v; v.f = x;
  unsigned r = v.u + 0x7FFFu + ((v.u >> 16) & 1u);
  return (unsigned short)(r >> 16);
}
__device__ __forceinline__ float sigf(float x) { return 1.f / (1.f + __expf(-x)); }
__device__ __forceinline__ float tanhf_(float x) {
  float t = __expf(-2.f * fabsf(x));
  float r = (1.f - t) / (1.f + t);
  return x < 0.f ? -r : r;
}

__global__ void k_zero(unsigned* __restrict__ p, int n) {
  int i = blockIdx.x * 256 + threadIdx.x;
  if (i < n) p[i] = 0u;
}

// W' bf16 [2][2048][832] = [W_hh | W_ih | 0-pad] per gate row
__global__ void k_prep_w(const float* __restrict__ Wihf, const float* __restrict__ Whhf,
                         const float* __restrict__ Wihb, const float* __restrict__ Whhb,
                         unsigned short* __restrict__ Wp) {
  int idx = blockIdx.x * 256 + threadIdx.x;
  if (idx >= 2 * G4 * KW) return;
  int d = idx / (G4 * KW);
  int rem = idx % (G4 * KW);
  int R = rem / KW, k = rem % KW;
  const float* Whh = d ? Whhb : Whhf;
  const float* Wih = d ? Wihb : Wihf;
  float v = 0.f;
  if (k < HD) v = Whh[R * HD + k];
  else if (k < HD + ED) v = Wih[R * ED + (k - HD)];
  Wp[idx] = f2bf(v);
}

// xe bf16 [S][B][320] = emb[tok] padded
__global__ void k_prep_xe(const int* __restrict__ x, const float* __restrict__ emb,
                          unsigned short* __restrict__ xe) {
  const int bidx = blockIdx.x;           // t*NB + b
  const int t = bidx / NB, b = bidx % NB;
  const int tok = x[b * SQ + t];         // x is (B,1,S)
  unsigned short* dst = xe + (size_t)(t * NB + b) * EP;
  const float* src = emb + (size_t)tok * ED;
  for (int e = threadIdx.x; e < EP; e += 64)
    dst[e] = (e < ED) ? f2bf(src[e]) : (unsigned short)0;
}

#define MFMA __builtin_amdgcn_mfma_f32_16x16x32_bf16

__global__ __launch_bounds__(256, 1) void lstm_scan(
    const unsigned short* __restrict__ Wp,    // [2][2048][832] bf16
    const unsigned short* __restrict__ xe,    // [S][B][320] bf16
    const float* __restrict__ bias_f,
    const float* __restrict__ bias_b,
    unsigned short* __restrict__ hbuf,        // [2 parity][2 dir][B][H] bf16
    float* __restrict__ hfin,                 // [2][B][H] f32
    unsigned* __restrict__ flags)             // [8 groups][64] u32 (256B stride)
{
  extern __shared__ unsigned short wlds[];    // [13][64][64] bf16, XOR-swizzled = 106496 B
  const int p = blockIdx.x;
  const int g8 = p & 7;        // group id (d,bg)
  const int d  = g8 >> 2;
  const int bg = g8 & 3;
  const int ct = p >> 3;       // col tile (16 h-cols), 0..31
  const int tid = threadIdx.x;
  const int lane = tid & 63;
  const int wv = tid >> 6;     // wave -> batch sub-block of 16
  const int q = lane >> 4;     // k-slice 0..3
  const int lm = lane & 15;
  const int xo = lm & 7;       // LDS XOR-swizzle key

  // ---- load W' tile into LDS once (XOR-swizzled: block c8 at (c8 ^ (row&7))) ----
  {
    const unsigned short* wsrc = Wp + (size_t)d * G4 * KW;
    for (int u = tid; u < 13 * 64 * 8; u += 256) {
      int ch  = u >> 9;          // chunk 0..12
      int rem = u & 511;
      int row = rem >> 3, c8 = rem & 7;
      int R = ((row >> 4) << 9) + (ct << 4) + (row & 15);  // gate*512 + ct*16 + j
      bf16x8 v = *(const bf16x8*)(wsrc + (size_t)R * KW + (ch << 6) + (c8 << 3));
      *(bf16x8*)&wlds[(ch * 64 + row) * 64 + ((c8 ^ (row & 7)) << 3)] = v;
    }
  }
  __syncthreads();

  const float* bias = d ? bias_b : bias_f;
  const int ncol = (ct << 4) | lm;
  const float Bi = bias[ncol];
  const float Bf = bias[512 + ncol];
  const float Bg = bias[1024 + ncol];
  const float Bo = bias[1536 + ncol];

  float cr[4] = {0.f, 0.f, 0.f, 0.f};
  const int arow = wv * 16 + lm;

  for (int t = 0; t < SQ; ++t) {
    const int tx = d ? (SQ - 1 - t) : t;
    f32x4 acc0 = {Bi, Bi, Bi, Bi};
    f32x4 acc1 = {Bf, Bf, Bf, Bf};
    f32x4 acc2 = {Bg, Bg, Bg, Bg};
    f32x4 acc3 = {Bo, Bo, Bo, Bo};

    // ---- xe phase (K 512..831): h-independent, runs before the poll ----
    const unsigned short* xrow = xe + ((size_t)tx * NB + bg * 64 + arow) * EP + (q << 3);
    #pragma unroll
    for (int ch = 0; ch < 5; ++ch) {
      #pragma unroll
      for (int kk = 0; kk < 2; ++kk) {
        bf16x8 a = *(const bf16x8*)(xrow + (ch << 6) + (kk << 5));
        const unsigned short* wb = &wlds[((8 + ch) * 64) * 64];
        const int off = ((((kk << 2) | q) ^ xo) << 3);
        bf16x8 b0 = *(const bf16x8*)&wb[(     lm) * 64 + off];
        bf16x8 b1 = *(const bf16x8*)&wb[(16 + lm) * 64 + off];
        bf16x8 b2 = *(const bf16x8*)&wb[(32 + lm) * 64 + off];
        bf16x8 b3 = *(const bf16x8*)&wb[(48 + lm) * 64 + off];
        acc0 = MFMA(a, b0, acc0, 0, 0, 0);
        acc1 = MFMA(a, b1, acc1, 0, 0, 0);
        acc2 = MFMA(a, b2, acc2, 0, 0, 0);
        acc3 = MFMA(a, b3, acc3, 0, 0, 0);
      }
    }

    // ---- wait for step t-1 (all 32 WGs of this group); no fence ----
    if (t > 0) {
      if (tid < 64) {
        const unsigned tgt = (unsigned)t;
        while (1) {
          unsigned v = tgt;
          if (lane < 32)
            v = __hip_atomic_load(&flags[g8 * 64 + lane], __ATOMIC_RELAXED, __HIP_MEMORY_SCOPE_AGENT);
          if (__all((int)(v >= tgt))) break;
          __builtin_amdgcn_s_sleep(1);
        }
      }
      __syncthreads();
    }

    // ---- h phase (K 0..511): IF$-coherent loads (sc0|sc1), then MFMAs ----
    const unsigned short* hrow =
        hbuf + ((size_t)((t & 1) * 2 + d) * NB + bg * 64 + arow) * HD + (q << 3);
    i32x4 ha[16];
    #pragma unroll
    for (int u = 0; u < 16; ++u) {
      const unsigned short* pa = hrow + u * 32;   // (ch*2+kk)*32 shorts = ch*64+kk*32
      asm volatile("global_load_dwordx4 %0, %1, off sc0 sc1"
                   : "=v"(ha[u]) : "v"(pa) : "memory");
    }
    asm volatile("s_waitcnt vmcnt(0)" ::: "memory");
    __builtin_amdgcn_sched_barrier(0);
    #pragma unroll
    for (int ch = 0; ch < 8; ++ch) {
      #pragma unroll
      for (int kk = 0; kk < 2; ++kk) {
        bf16x8 a = __builtin_bit_cast(bf16x8, ha[ch * 2 + kk]);
        const unsigned short* wb = &wlds[(ch * 64) * 64];
        const int off = ((((kk << 2) | q) ^ xo) << 3);
        bf16x8 b0 = *(const bf16x8*)&wb[(     lm) * 64 + off];
        bf16x8 b1 = *(const bf16x8*)&wb[(16 + lm) * 64 + off];
        bf16x8 b2 = *(const bf16x8*)&wb[(32 + lm) * 64 + off];
        bf16x8 b3 = *(const bf16x8*)&wb[(48 + lm) * 64 + off];
        acc0 = MFMA(a, b0, acc0, 0, 0, 0);
        acc1 = MFMA(a, b1, acc1, 0, 0, 0);
        acc2 = MFMA(a, b2, acc2, 0, 0, 0);
        acc3 = MFMA(a, b3, acc3, 0, 0, 0);
      }
    }

    // ---- epilogue: gates, c in regs, pack h pairs, IF$ stores, flag ----
    unsigned short* hout = hbuf + ((size_t)(((t & 1) ^ 1) * 2 + d) * NB) * HD;
    unsigned w0, w1, w2, w3; float hv0, hv1, hv2, hv3;
    {
      float c0 = sigf(acc1[0]) * cr[0] + sigf(acc0[0]) * tanhf_(acc2[0]);
      float c1 = sigf(acc1[1]) * cr[1] + sigf(acc0[1]) * tanhf_(acc2[1]);
      float c2 = sigf(acc1[2]) * cr[2] + sigf(acc0[2]) * tanhf_(acc2[2]);
      float c3 = sigf(acc1[3]) * cr[3] + sigf(acc0[3]) * tanhf_(acc2[3]);
      hv0 = sigf(acc3[0]) * tanhf_(c0); hv1 = sigf(acc3[1]) * tanhf_(c1);
      hv2 = sigf(acc3[2]) * tanhf_(c2); hv3 = sigf(acc3[3]) * tanhf_(c3);
      cr[0] = c0; cr[1] = c1; cr[2] = c2; cr[3] = c3;
      unsigned u0 = f2bf(hv0), u1 = f2bf(hv1), u2 = f2bf(hv2), u3 = f2bf(hv3);
      unsigned p0 = (unsigned)__shfl_xor((int)u0, 1, 64) & 0xFFFFu;
      unsigned p1 = (unsigned)__shfl_xor((int)u1, 1, 64) & 0xFFFFu;
      unsigned p2 = (unsigned)__shfl_xor((int)u2, 1, 64) & 0xFFFFu;
      unsigned p3 = (unsigned)__shfl_xor((int)u3, 1, 64) & 0xFFFFu;
      const bool od = (lm & 1);
      w0 = od ? (p0 | (u0 << 16)) : (u0 | (p0 << 16));
      w1 = od ? (p1 | (u1 << 16)) : (u1 | (p1 << 16));
      w2 = od ? (p2 | (u2 << 16)) : (u2 | (p2 << 16));
      w3 = od ? (p3 | (u3 << 16)) : (u3 | (p3 << 16));
    }
    if (t < SQ - 1) {
      const unsigned wa = (lm & 1) ? w2 : w0;
      const unsigned wb2 = (lm & 1) ? w3 : w1;
      const int brow0 = bg * 64 + wv * 16 + q * 4 + ((lm & 1) << 1);
      const unsigned short* a0 = hout + (size_t)brow0 * HD + (ncol & ~1);
      const unsigned short* a1 = a0 + HD;
      asm volatile("global_store_dword %0, %1, off sc0 sc1" :: "v"(a0), "v"(wa) : "memory");
      asm volatile("global_store_dword %0, %1, off sc0 sc1" :: "v"(a1), "v"(wb2) : "memory");
      asm volatile("s_waitcnt vmcnt(0)" ::: "memory");   // per-wave drain to IF$
      __syncthreads();                                    // all 4 waves drained
      if (tid == 0)
        __hip_atomic_store(&flags[g8 * 64 + ct], (unsigned)(t + 1),
                           __ATOMIC_RELAXED, __HIP_MEMORY_SCOPE_AGENT);
    } else {
      const int brow = bg * 64 + wv * 16 + q * 4;
      hfin[(d * NB + brow + 0) * HD + ncol] = hv0;
      hfin[(d * NB + brow + 1) * HD + ncol] = hv1;
      hfin[(d * NB + brow + 2) * HD + ncol] = hv2;
      hfin[(d * NB + brow + 3) * HD + ncol] = hv3;
    }
  }
}

__global__ void k_out(const float* __restrict__ hfin, const float* __restrict__ Wo,
                      const float* __restrict__ bo, float* __restrict__ out) {
  const int b = blockIdx.x;
  const int tid = threadIdx.x;
  float s = 0.f;
  for (int k = tid; k < 1024; k += 256)
    s += hfin[((k >> 9) * NB + b) * HD + (k & 511)] * Wo[k];
  #pragma unroll
  for (int o = 32; o > 0; o >>= 1) s += __shfl_down(s, o, 64);
  __shared__ float red[4];
  if ((tid & 63) == 0) red[tid >> 6] = s;
  __syncthreads();
  if (tid == 0) out[b] = red[0] + red[1] + red[2] + red[3] + bo[0];
}

extern "C" void kernel_launch(void* const* d_in, const int* in_sizes, int n_in,
                              void* d_out, int out_size, void* d_ws, size_t ws_size,
                              hipStream_t stream) {
  const int*   x    = (const int*)d_in[0];
  const float* emb  = (const float*)d_in[1];
  const float* Wihf = (const float*)d_in[2];
  const float* Whhf = (const float*)d_in[3];
  const float* bf   = (const float*)d_in[4];
  const float* Wihb = (const float*)d_in[5];
  const float* Whhb = (const float*)d_in[6];
  const float* bb   = (const float*)d_in[7];
  const float* Wo   = (const float*)d_in[8];
  const float* bo   = (const float*)d_in[9];
  float* out = (float*)d_out;

  // ws layout:
  //   Wp    @ 0          : 2*2048*832*2  = 6,815,744
  //   xe    @ 6,815,744  : 256*256*320*2 = 41,943,040
  //   hbuf  @ 48,758,784 : 2*2*256*512*2 = 1,048,576
  //   flags @ 49,807,360 : 8*64*4        = 2,048
  //   hfin  @ 49,809,408 : 2*256*512*4   = 1,048,576
  char* ws = (char*)d_ws;
  unsigned short* Wp   = (unsigned short*)(ws + 0);
  unsigned short* xe   = (unsigned short*)(ws + 6815744);
  unsigned short* hbuf = (unsigned short*)(ws + 48758784);
  unsigned*       flg  = (unsigned*)(ws + 49807360);
  float*          hfin = (float*)(ws + 49809408);

  k_zero<<<1026, 256, 0, stream>>>((unsigned*)(ws + 48758784), 262656);
  k_prep_w<<<(2 * G4 * KW + 255) / 256, 256, 0, stream>>>(Wihf, Whhf, Wihb, Whhb, Wp);
  k_prep_xe<<<SQ * NB, 64, 0, stream>>>(x, emb, xe);

  const int ldsBytes = 13 * 64 * 64 * 2;  // 106,496
  hipFuncSetAttribute((const void*)lstm_scan,
                      hipFuncAttributeMaxDynamicSharedMemorySize, ldsBytes);

  void* args[] = { (void*)&Wp, (void*)&xe, (void*)&bf, (void*)&bb,
                   (void*)&hbuf, (void*)&hfin, (void*)&flg };
  hipLaunchCooperativeKernel((const void*)lstm_scan, dim3(256), dim3(256), args,
                             ldsBytes, stream);

  k_out<<<NB, 256, 0, stream>>>(hfin, Wo, bo, out);
}